// Round 12
// baseline (277.461 us; speedup 1.0000x reference)
//
#include <hip/hip_runtime.h>

#define NN 10000
#define NNP 10048
#define NE 160000
#define NG 64
#define HID 128
#define NL 3
#define CAP 64      // per-node edge slots (Poisson(16); P(deg>64) ~ 1e-20)

typedef float floatx4 __attribute__((ext_vector_type(4)));
typedef _Float16 f16x8 __attribute__((ext_vector_type(8)));
typedef __fp16 f16x2 __attribute__((ext_vector_type(2)));

__device__ __forceinline__ float fsig(float x){
  return __builtin_amdgcn_rcpf(1.f + __expf(-x));
}

// repack domain: wnf only layers 1,2 (layer 0 UV comes from raw m1 in setup)
#define RZ_A (2*65536)
#define RZ_B (RZ_A + NL*32768)
#define RZ_C (RZ_B + NL*32768)
#define RZ_D (RZ_C + NL*256)     // = 328448 = 1283*256
#define RB1  1283
#define RB2  (RB1 + 625)         // edge-placement blocks (625*256 = 160000)
#define RB3  (RB2 + 314)         // embed+UV0 blocks (2 tiles each)

// ---------------- setup: repack || edge binning || embed+UV0 ----------------
__global__ __launch_bounds__(256) void k_setup(
    const float* __restrict__ m1, const float* __restrict__ m2,
    const float* __restrict__ mg, const float* __restrict__ m1b,
    const int* __restrict__ ei, const float* __restrict__ ea,
    const float* __restrict__ x,
    const float* __restrict__ eW, const float* __restrict__ eB,
    const float* __restrict__ eG, const float* __restrict__ eBB,
    _Float16* __restrict__ wnf, _Float16* __restrict__ w2f,
    _Float16* __restrict__ gwf, float* __restrict__ w256,
    int* __restrict__ deg, int2* __restrict__ epk,
    float* __restrict__ hg, _Float16* __restrict__ hfg, _Float16* __restrict__ UV0)
{
  const int bid = blockIdx.x, tid = threadIdx.x;
  if (bid < RB1){
    int i = bid*256 + tid;
    if (i < RZ_A){
      int l = (i>>16) + 1, j = i & 65535;
      int t=j&7, col=(j>>3)&15, quad=(j>>7)&3, s=(j>>9)&3, mb=(j>>11)&31;
      int o = mb*16+col, k = s*32+quad*8+t;
      float v = (o<256) ? m1[l*65792 + o*257 + k] : m1[l*65792 + (o-256)*257 + 128 + k];
      wnf[i] = (_Float16)v;
    } else if (i < RZ_B){
      int j=i-RZ_A; int l=j>>15; j&=32767;
      int t=j&7, col=(j>>3)&15, quad=(j>>7)&3, s=(j>>9)&7, mb=(j>>12)&7;
      w2f[(l<<15)+j] = (_Float16)m2[l*32768 + (mb*16+col)*256 + s*32+quad*8+t];
    } else if (i < RZ_C){
      int j=i-RZ_B; int l=j>>15; j&=32767;
      int t=j&7, col=(j>>3)&15, quad=(j>>7)&3, s=(j>>9)&7, mb=(j>>12)&7;
      gwf[(l<<15)+j] = (_Float16)mg[l*32768 + (mb*16+col)*256 + s*32+quad*8+t];
    } else if (i < RZ_D){
      int j=i-RZ_C; int l=j>>8, o=j&255;
      w256[j] = m1[l*65792 + o*257 + 256];
    }
    return;
  }
  if (bid < RB2){
    int e = (bid-RB1)*256 + tid;
    int d = ei[NE + e];
    int slot = atomicAdd(&deg[d], 1) & (CAP-1);
    int2 pk; pk.x = ei[e]; pk.y = __float_as_int(ea[e]);
    epk[(size_t)d*CAP + slot] = pk;
    return;
  }
  // ---- embed (16 nodes) + layer-0 UV from raw m1 ; two tiles per block ----
  __shared__ _Float16 HFs[16][136];
  for (int tt=0; tt<2; tt++){
    const int tb = (bid - RB2)*2 + tt;
    {
      int n = tid>>4, q = tid&15;
      int node = tb*16 + n;
      float x0=0.f, x1=0.f, x2=0.f;
      if (node < NN){ x0=x[node*3]; x1=x[node*3+1]; x2=x[node*3+2]; }
      float v[8], s=0.f, s2=0.f;
#pragma unroll
      for (int j=0;j<8;j++){
        int c = q*8+j;
        v[j] = eW[c*3]*x0 + eW[c*3+1]*x1 + eW[c*3+2]*x2 + eB[c];
        s += v[j]; s2 += v[j]*v[j];
      }
#pragma unroll
      for (int m=1;m<16;m<<=1){ s += __shfl_xor(s,m,64); s2 += __shfl_xor(s2,m,64); }
      float mean = s*(1.f/128.f);
      float var  = s2*(1.f/128.f) - mean*mean;
      float rsq  = rsqrtf(var + 1e-5f);
      float ho[8];
#pragma unroll
      for (int j=0;j<8;j++){
        int c = q*8+j;
        float y = (v[j]-mean)*rsq*eG[c] + eBB[c];
        ho[j] = y * fsig(y);
      }
      *(float4*)(hg + (size_t)node*HID + q*8)     = make_float4(ho[0],ho[1],ho[2],ho[3]);
      *(float4*)(hg + (size_t)node*HID + q*8 + 4) = make_float4(ho[4],ho[5],ho[6],ho[7]);
      union { f16x2 h2[4]; uint4 u; } pk;
      pk.h2[0] = __builtin_amdgcn_cvt_pkrtz(ho[0],ho[1]);
      pk.h2[1] = __builtin_amdgcn_cvt_pkrtz(ho[2],ho[3]);
      pk.h2[2] = __builtin_amdgcn_cvt_pkrtz(ho[4],ho[5]);
      pk.h2[3] = __builtin_amdgcn_cvt_pkrtz(ho[6],ho[7]);
      *(uint4*)(hfg + (size_t)node*HID + q*8) = pk.u;
      *(uint4*)(&HFs[n][q*8]) = pk.u;
    }
    __syncthreads();
    {
      const int wv=tid>>6, lane=tid&63, col=lane&15, quad=lane>>4;
      const int node = tb*16 + col;
      f16x8 bf[4];
#pragma unroll
      for (int s=0;s<4;s++) bf[s] = *(const f16x8*)(&HFs[col][s*32+quad*8]);
#pragma unroll
      for (int mt=0;mt<8;mt++){
        int row = (wv*8+mt)*16 + col;           // out index 0..511
        const float* wrow = (row<256) ? (m1 + row*257) : (m1 + (row-256)*257 + 128);
        floatx4 acc = (floatx4)(0.f);
#pragma unroll
        for (int s=0;s<4;s++){
          const float* wp = wrow + s*32 + quad*8;
          union { f16x2 h2[4]; f16x8 v8; } pa;
          pa.h2[0] = __builtin_amdgcn_cvt_pkrtz(wp[0],wp[1]);
          pa.h2[1] = __builtin_amdgcn_cvt_pkrtz(wp[2],wp[3]);
          pa.h2[2] = __builtin_amdgcn_cvt_pkrtz(wp[4],wp[5]);
          pa.h2[3] = __builtin_amdgcn_cvt_pkrtz(wp[6],wp[7]);
          acc = __builtin_amdgcn_mfma_f32_16x16x32_f16(pa.v8, bf[s], acc, 0,0,0);
        }
        int o0 = (wv*8+mt)*16 + quad*4;
        float4 bv = (o0 < 256) ? *(const float4*)(m1b + o0) : make_float4(0.f,0.f,0.f,0.f);
        union { f16x2 h2[2]; uint2 u; } pk;
        pk.h2[0] = __builtin_amdgcn_cvt_pkrtz(acc[0]+bv.x, acc[1]+bv.y);
        pk.h2[1] = __builtin_amdgcn_cvt_pkrtz(acc[2]+bv.z, acc[3]+bv.w);
        *(uint2*)(UV0 + (size_t)node*512 + o0) = pk.u;
      }
    }
    __syncthreads();   // HFs reused by next tile
  }
}

// ---------------- fused layer: agg + GEMM2 + gate + LN + next-layer UV ----------------
__global__ __launch_bounds__(512) void k_layer(
    const _Float16* __restrict__ uvin, _Float16* __restrict__ uvout,
    const int2* __restrict__ epk, const int* __restrict__ deg,
    const float* __restrict__ w256l,
    const _Float16* __restrict__ w2fl, const float* __restrict__ b2l,
    const _Float16* __restrict__ gwfl, const float* __restrict__ gbl,
    const float* __restrict__ lngl, const float* __restrict__ lnbl,
    float* __restrict__ hg, _Float16* __restrict__ hfg,
    const _Float16* __restrict__ wnfN, const float* __restrict__ m1bN)
{
  __shared__ _Float16 AggH[16][264];  // [0..127] aggr-f16 (after B); [128..255] new-hf (after C)
  __shared__ float    Agg[16][132];
  __shared__ float    reds[8][16], reds2[8][16];
  const int tid = threadIdx.x;
  const int wv = tid>>6, lane = tid&63;
  const int col = lane&15, quad = lane>>4;
  const int half = lane>>5, sub = lane&31;
  const int n0 = blockIdx.x*16;

  // ---- A: aggregation; wave wv -> nodes {wv*2, wv*2+1} interleaved; 8 dims/lane;
  //      edges split by half (even/odd). 4 independent gather chains in flight. ----
  {
    const int el = sub*8;
    float wcv[8];
    { float4 a = *(const float4*)(w256l + el);
      float4 b = *(const float4*)(w256l + el + 4);
      wcv[0]=a.x; wcv[1]=a.y; wcv[2]=a.z; wcv[3]=a.w;
      wcv[4]=b.x; wcv[5]=b.y; wcv[6]=b.z; wcv[7]=b.w; }

    const int nA = n0 + wv*2, nB = nA + 1;
    f16x8 uA = *(const f16x8*)(uvin + (size_t)nA*512 + el);
    f16x8 uB = *(const f16x8*)(uvin + (size_t)nB*512 + el);
    float UA[8], UB[8], aA[8], aB[8];
#pragma unroll
    for (int j=0;j<8;j++){ UA[j]=(float)uA[j]; UB[j]=(float)uB[j]; aA[j]=0.f; aB[j]=0.f; }
    int dA = deg[nA]; if (dA > CAP) dA = CAP;
    int dB = deg[nB]; if (dB > CAP) dB = CAP;
    const int2* ppA = epk + (size_t)nA*CAP;
    const int2* ppB = epk + (size_t)nB*CAP;

    f16x8 vA, vB; float eA=0.f, eB=0.f;
    if (half < dA){ int2 p = ppA[half]; eA = __int_as_float(p.y);
                    vA = *(const f16x8*)(uvin + (size_t)p.x*512 + 256 + el); }
    if (half < dB){ int2 p = ppB[half]; eB = __int_as_float(p.y);
                    vB = *(const f16x8*)(uvin + (size_t)p.x*512 + 256 + el); }
    int dmax = dA > dB ? dA : dB;
    for (int r = half; r < dmax; r += 2){
      bool okA = r < dA, okB = r < dB;
      f16x8 cA = vA, cB = vB;
      float ecA = eA, ecB = eB;
      int rn = r + 2;
      if (rn < dA){ int2 p = ppA[rn]; eA = __int_as_float(p.y);
                    vA = *(const f16x8*)(uvin + (size_t)p.x*512 + 256 + el); }
      if (rn < dB){ int2 p = ppB[rn]; eB = __int_as_float(p.y);
                    vB = *(const f16x8*)(uvin + (size_t)p.x*512 + 256 + el); }
      if (okA){
#pragma unroll
        for (int j=0;j<8;j++){
          float f = UA[j] + (float)cA[j] + ecA*wcv[j];
          aA[j] += f*fsig(f);
        }
      }
      if (okB){
#pragma unroll
        for (int j=0;j<8;j++){
          float f = UB[j] + (float)cB[j] + ecB*wcv[j];
          aB[j] += f*fsig(f);
        }
      }
    }
#pragma unroll
    for (int j=0;j<8;j++){
      aA[j] += __shfl_xor(aA[j], 32, 64);
      aB[j] += __shfl_xor(aB[j], 32, 64);
    }
    if (half == 0){
      union { f16x2 h2[4]; uint4 u; } pk;
      pk.h2[0] = __builtin_amdgcn_cvt_pkrtz(aA[0],aA[1]);
      pk.h2[1] = __builtin_amdgcn_cvt_pkrtz(aA[2],aA[3]);
      pk.h2[2] = __builtin_amdgcn_cvt_pkrtz(aA[4],aA[5]);
      pk.h2[3] = __builtin_amdgcn_cvt_pkrtz(aA[6],aA[7]);
      *(uint4*)(&AggH[wv*2][el]) = pk.u;
      pk.h2[0] = __builtin_amdgcn_cvt_pkrtz(aB[0],aB[1]);
      pk.h2[1] = __builtin_amdgcn_cvt_pkrtz(aB[2],aB[3]);
      pk.h2[2] = __builtin_amdgcn_cvt_pkrtz(aB[4],aB[5]);
      pk.h2[3] = __builtin_amdgcn_cvt_pkrtz(aB[6],aB[7]);
      *(uint4*)(&AggH[wv*2+1][el]) = pk.u;
    }
  }
  __syncthreads();

  // ---- B: GEMM2 over silu-agg; wave wv -> outs [wv*16,+16) ----
  floatx4 acc2 = (floatx4)(0.f);
  {
    const _Float16* wb2 = w2fl + quad*128 + col*8;
#pragma unroll
    for (int s=0;s<8;s++){
      f16x8 b = *(const f16x8*)(&AggH[col][s*32 + quad*8]);
      f16x8 a = *(const f16x8*)(wb2 + (size_t)(wv*8+s)*512);
      acc2 = __builtin_amdgcn_mfma_f32_16x16x32_f16(a, b, acc2, 0,0,0);
    }
  }
  __syncthreads();
  {
    float degf = (float)min(deg[n0+col], CAP);
    int outb = wv*16 + quad*4;
    float4 b2v = *(const float4*)(b2l + outb);
    float v0 = acc2[0] + degf*b2v.x;
    float v1 = acc2[1] + degf*b2v.y;
    float v2 = acc2[2] + degf*b2v.z;
    float v3 = acc2[3] + degf*b2v.w;
    *(float4*)(&Agg[col][outb]) = make_float4(v0,v1,v2,v3);
    union { f16x2 h2[2]; uint2 u; } pk;
    pk.h2[0] = __builtin_amdgcn_cvt_pkrtz(v0,v1);
    pk.h2[1] = __builtin_amdgcn_cvt_pkrtz(v2,v3);
    *(uint2*)(&AggH[col][outb]) = pk.u;
  }
  __syncthreads();

  // ---- C: gate GEMM over [hf(global) ; aggr(LDS)], residual, LN ----
  floatx4 accg = (floatx4)(0.f);
  {
    const int node = n0 + col;
    const _Float16* wbg = gwfl + quad*128 + col*8;
#pragma unroll
    for (int s=0;s<4;s++){
      f16x8 b = *(const f16x8*)(hfg + (size_t)node*HID + s*32 + quad*8);
      f16x8 a = *(const f16x8*)(wbg + (size_t)(wv*8+s)*512);
      accg = __builtin_amdgcn_mfma_f32_16x16x32_f16(a, b, accg, 0,0,0);
    }
#pragma unroll
    for (int s=4;s<8;s++){
      f16x8 b = *(const f16x8*)(&AggH[col][(s-4)*32 + quad*8]);
      f16x8 a = *(const f16x8*)(wbg + (size_t)(wv*8+s)*512);
      accg = __builtin_amdgcn_mfma_f32_16x16x32_f16(a, b, accg, 0,0,0);
    }
  }
  const int outb = wv*16 + quad*4;
  const int node = n0 + col;
  float vvv[4], ss=0.f, ss2=0.f;
  {
    float4 gbv = *(const float4*)(gbl + outb);
    float4 av  = *(const float4*)(&Agg[col][outb]);
    float4 hv  = *(const float4*)(hg + (size_t)node*HID + outb);
    float gg[4] = {gbv.x,gbv.y,gbv.z,gbv.w};
    float aa[4] = {av.x,av.y,av.z,av.w};
    float hh[4] = {hv.x,hv.y,hv.z,hv.w};
#pragma unroll
    for (int r=0;r<4;r++){
      float gate = fsig(accg[r] + gg[r]);
      float v = hh[r] + gate*aa[r] + (1.f-gate)*hh[r];
      vvv[r] = v; ss += v; ss2 += v*v;
    }
  }
  ss  += __shfl_xor(ss, 16, 64);  ss  += __shfl_xor(ss, 32, 64);
  ss2 += __shfl_xor(ss2, 16, 64); ss2 += __shfl_xor(ss2, 32, 64);
  if (quad == 0){ reds[wv][col] = ss; reds2[wv][col] = ss2; }
  __syncthreads();

  {
    float S=0.f, S2=0.f;
#pragma unroll
    for (int w=0;w<8;w++){ S += reds[w][col]; S2 += reds2[w][col]; }
    float mean = S*(1.f/128.f);
    float var  = S2*(1.f/128.f) - mean*mean;
    float rsq  = rsqrtf(var + 1e-5f);
    float4 gv = *(const float4*)(lngl + outb);
    float4 bv = *(const float4*)(lnbl + outb);
    float o0 = (vvv[0]-mean)*rsq*gv.x + bv.x;
    float o1 = (vvv[1]-mean)*rsq*gv.y + bv.y;
    float o2 = (vvv[2]-mean)*rsq*gv.z + bv.z;
    float o3 = (vvv[3]-mean)*rsq*gv.w + bv.w;
    *(float4*)(hg + (size_t)node*HID + outb) = make_float4(o0,o1,o2,o3);
    union { f16x2 h2[2]; uint2 u; } pk;
    pk.h2[0] = __builtin_amdgcn_cvt_pkrtz(o0,o1);
    pk.h2[1] = __builtin_amdgcn_cvt_pkrtz(o2,o3);
    *(uint2*)(hfg + (size_t)node*HID + outb) = pk.u;
    *(uint2*)(&AggH[col][128 + outb]) = pk.u;
  }
  __syncthreads();

  // ---- D: next layer's UV ----
  if (uvout){
    f16x8 bf[4];
#pragma unroll
    for (int s=0;s<4;s++) bf[s] = *(const f16x8*)(&AggH[col][128 + s*32 + quad*8]);
    floatx4 au[4];
#pragma unroll
    for (int i=0;i<4;i++) au[i] = (floatx4)(0.f);
    const _Float16* wbn = wnfN + quad*128 + col*8;
#pragma unroll
    for (int s=0;s<4;s++)
#pragma unroll
      for (int mt=0;mt<4;mt++){
        f16x8 a = *(const f16x8*)(wbn + (size_t)((wv*4+mt)*4+s)*512);
        au[mt] = __builtin_amdgcn_mfma_f32_16x16x32_f16(a, bf[s], au[mt], 0,0,0);
      }
#pragma unroll
    for (int mt=0;mt<4;mt++){
      int o0i = (wv*4+mt)*16 + quad*4;
      float4 buv = (o0i < 256) ? *(const float4*)(m1bN + o0i) : make_float4(0.f,0.f,0.f,0.f);
      union { f16x2 h2[2]; uint2 u; } pu;
      pu.h2[0] = __builtin_amdgcn_cvt_pkrtz(au[mt][0]+buv.x, au[mt][1]+buv.y);
      pu.h2[1] = __builtin_amdgcn_cvt_pkrtz(au[mt][2]+buv.z, au[mt][3]+buv.w);
      *(uint2*)(uvout + (size_t)node*512 + o0i) = pu.u;
    }
  }
}

// ---------------- pooling (binary search) + projector ----------------
__global__ __launch_bounds__(512) void k_fin(
    const float* __restrict__ h, const int* __restrict__ batch,
    const float* __restrict__ p1W, const float* __restrict__ p1b,
    const float* __restrict__ l1g, const float* __restrict__ l1b,
    const float* __restrict__ p2W, const float* __restrict__ p2b,
    const float* __restrict__ l2g, const float* __restrict__ l2b,
    float* __restrict__ out)
{
  __shared__ float xs[4][128];
  __shared__ float xg[128], pbuf[128], redf[4];
  const int g = blockIdx.x, tid = threadIdx.x;
  const int c = tid & 127, part = tid >> 7;
  int lo, hi;
  { int L=0, r=NN;
    while (L<r){ int m=(L+r)>>1; if (batch[m]<g) L=m+1; else r=m; }
    lo = L; r = NN;
    while (L<r){ int m=(L+r)>>1; if (batch[m]<g+1) L=m+1; else r=m; }
    hi = L; }
  float s = 0.f;
  for (int n = lo+part; n < hi; n += 4) s += h[(size_t)n*HID + c];
  xs[part][c] = s;
  __syncthreads();
  if (tid < 128){
    float cnt = (float)(hi-lo);
    float S = xs[0][c]+xs[1][c]+xs[2][c]+xs[3][c];
    float xgv = S * (1.f/fmaxf(cnt,1.f) + 1.f/(cnt + 1e-6f));
    out[NG*64 + g*HID + c] = xgv;
    xg[c] = xgv;
  }
  __syncthreads();
  {
    float vp = 0.f;
    for (int k = part*32; k < (part+1)*32; k++) vp += xg[k]*p1W[c*HID + k];
    xs[part][c] = vp;
  }
  __syncthreads();
  float v = 0.f;
  if (tid < 128){
    v = p1b[c] + xs[0][c]+xs[1][c]+xs[2][c]+xs[3][c];
    float sv=v, sv2=v*v;
#pragma unroll
    for (int m=1;m<64;m<<=1){ sv+=__shfl_xor(sv,m,64); sv2+=__shfl_xor(sv2,m,64); }
    if ((c&63)==0){ redf[(c>>6)*2]=sv; redf[(c>>6)*2+1]=sv2; }
  }
  __syncthreads();
  if (tid < 128){
    float S=redf[0]+redf[2], S2=redf[1]+redf[3];
    float mean=S*(1.f/128.f), var=S2*(1.f/128.f)-mean*mean;
    float y=(v-mean)*rsqrtf(var+1e-5f)*l1g[c]+l1b[c];
    pbuf[c] = y*fsig(y);
  }
  __syncthreads();
  if (tid < 64){
    float z = p2b[tid];
    for (int k=0;k<HID;k++) z += pbuf[k]*p2W[tid*HID + k];
    float t=z, t2=z*z;
#pragma unroll
    for (int m=1;m<64;m<<=1){ t+=__shfl_xor(t,m,64); t2+=__shfl_xor(t2,m,64); }
    float mn=t*(1.f/64.f), vr=t2*(1.f/64.f)-mn*mn;
    out[g*64 + tid] = (z-mn)*rsqrtf(vr+1e-5f)*l2g[tid]+l2b[tid];
  }
}

extern "C" void kernel_launch(void* const* d_in, const int* in_sizes, int n_in,
                              void* d_out, int out_size, void* d_ws, size_t ws_size,
                              hipStream_t stream){
  const float* x     = (const float*)d_in[0];
  const float* ea    = (const float*)d_in[1];
  const int*   ei    = (const int*)  d_in[2];
  const int*   batch = (const int*)  d_in[3];
  const float* embW  = (const float*)d_in[4];
  const float* embB  = (const float*)d_in[5];
  const float* embG  = (const float*)d_in[6];
  const float* embBe = (const float*)d_in[7];
  const float* m1W   = (const float*)d_in[8];
  const float* m1b   = (const float*)d_in[9];
  const float* m2W   = (const float*)d_in[10];
  const float* m2b   = (const float*)d_in[11];
  const float* gW    = (const float*)d_in[12];
  const float* gb    = (const float*)d_in[13];
  const float* lng   = (const float*)d_in[14];
  const float* lnb   = (const float*)d_in[15];
  const float* p1W   = (const float*)d_in[16];
  const float* p1b   = (const float*)d_in[17];
  const float* l1g   = (const float*)d_in[18];
  const float* l1b   = (const float*)d_in[19];
  const float* p2W   = (const float*)d_in[20];
  const float* p2b   = (const float*)d_in[21];
  const float* l2g   = (const float*)d_in[22];
  const float* l2b   = (const float*)d_in[23];

  char* p = (char*)d_ws;
  auto alloc = [&](size_t bytes){ char* r = p; p += (bytes + 255) & ~(size_t)255; return r; };
  float*     hg   = (float*)     alloc((size_t)NNP*HID*4);
  _Float16*  hfg  = (_Float16*)  alloc((size_t)NNP*HID*2);
  _Float16*  UVa  = (_Float16*)  alloc((size_t)NNP*512*2);
  _Float16*  UVb  = (_Float16*)  alloc((size_t)NNP*512*2);
  _Float16*  wnf  = (_Float16*)  alloc((size_t)2*65536*2);
  _Float16*  w2f  = (_Float16*)  alloc((size_t)NL*32768*2);
  _Float16*  gwf  = (_Float16*)  alloc((size_t)NL*32768*2);
  float*     w256 = (float*)     alloc((size_t)NL*256*4);
  int*       deg  = (int*)       alloc((size_t)NNP*4);
  int2*      epk  = (int2*)      alloc((size_t)NNP*CAP*8);

  hipMemsetAsync(deg, 0, (size_t)NNP*4, stream);

  k_setup<<<RB3, 256, 0, stream>>>(
      m1W, m2W, gW, m1b, ei, ea, x, embW, embB, embG, embBe,
      wnf, w2f, gwf, w256, deg, epk, hg, hfg, UVa);

  for (int l=0; l<NL; l++){
    bool last = (l == NL-1);
    _Float16* uvin  = (l&1) ? UVb : UVa;
    _Float16* uvout = last ? nullptr : ((l&1) ? UVa : UVb);
    k_layer<<<NNP/16, 512, 0, stream>>>(
        uvin, uvout, epk, deg,
        w256 + l*256, w2f + (size_t)l*32768, m2b + l*128,
        gwf + (size_t)l*32768, gb + l*128,
        lng + l*128, lnb + l*128,
        hg, hfg,
        last ? (const _Float16*)nullptr : (wnf + (size_t)l*65536),
        m1b + (last ? 0 : (l+1)*256));
  }
  k_fin<<<NG, 512, 0, stream>>>(hg, batch, p1W, p1b, l1g, l1b,
                                p2W, p2b, l2g, l2b, (float*)d_out);
}

// Round 13
// 251.620 us; speedup vs baseline: 1.1027x; 1.1027x over previous
//
#include <hip/hip_runtime.h>

#define NN 10000
#define NNP 10048
#define NE 160000
#define NG 64
#define HID 128
#define NL 3
#define CAP 64      // per-node edge slots (Poisson(16); P(deg>64) ~ 1e-20)

typedef float floatx4 __attribute__((ext_vector_type(4)));
typedef _Float16 f16x8 __attribute__((ext_vector_type(8)));
typedef __fp16 f16x2 __attribute__((ext_vector_type(2)));

__device__ __forceinline__ float fsig(float x){
  return __builtin_amdgcn_rcpf(1.f + __expf(-x));
}

// repack domain: wnf all 3 layers
#define RZ_A (NL*65536)
#define RZ_B (RZ_A + NL*32768)
#define RZ_C (RZ_B + NL*32768)
#define RZ_D (RZ_C + NL*256)     // = 393984
#define RB1  ((RZ_D + 255)/256)  // 1539
#define RB2  (RB1 + 625)         // edge-placement blocks
#define RB3  (RB2 + 628)         // embed blocks (1 tile each)

// ---------------- setup: repack || edge binning || embed ----------------
__global__ __launch_bounds__(256) void k_setup(
    const float* __restrict__ m1, const float* __restrict__ m2,
    const float* __restrict__ mg,
    const int* __restrict__ ei, const float* __restrict__ ea,
    const float* __restrict__ x,
    const float* __restrict__ eW, const float* __restrict__ eB,
    const float* __restrict__ eG, const float* __restrict__ eBB,
    _Float16* __restrict__ wnf, _Float16* __restrict__ w2f,
    _Float16* __restrict__ gwf, float* __restrict__ w256,
    int* __restrict__ deg, int2* __restrict__ epk,
    float* __restrict__ hg, _Float16* __restrict__ hfg)
{
  const int bid = blockIdx.x, tid = threadIdx.x;
  if (bid < RB1){
    int i = bid*256 + tid;
    if (i < RZ_A){
      int l = i>>16, j = i & 65535;
      int t=j&7, col=(j>>3)&15, quad=(j>>7)&3, s=(j>>9)&3, mb=(j>>11)&31;
      int o = mb*16+col, k = s*32+quad*8+t;
      float v = (o<256) ? m1[l*65792 + o*257 + k] : m1[l*65792 + (o-256)*257 + 128 + k];
      wnf[i] = (_Float16)v;
    } else if (i < RZ_B){
      int j=i-RZ_A; int l=j>>15; j&=32767;
      int t=j&7, col=(j>>3)&15, quad=(j>>7)&3, s=(j>>9)&7, mb=(j>>12)&7;
      w2f[(l<<15)+j] = (_Float16)m2[l*32768 + (mb*16+col)*256 + s*32+quad*8+t];
    } else if (i < RZ_C){
      int j=i-RZ_B; int l=j>>15; j&=32767;
      int t=j&7, col=(j>>3)&15, quad=(j>>7)&3, s=(j>>9)&7, mb=(j>>12)&7;
      gwf[(l<<15)+j] = (_Float16)mg[l*32768 + (mb*16+col)*256 + s*32+quad*8+t];
    } else if (i < RZ_D){
      int j=i-RZ_C; int l=j>>8, o=j&255;
      w256[j] = m1[l*65792 + o*257 + 256];
    }
    return;
  }
  if (bid < RB2){
    int e = (bid-RB1)*256 + tid;
    int d = ei[NE + e];
    int slot = atomicAdd(&deg[d], 1) & (CAP-1);
    int2 pk; pk.x = ei[e]; pk.y = __float_as_int(ea[e]);
    epk[(size_t)d*CAP + slot] = pk;
    return;
  }
  // ---- embed: 16 nodes, 16 threads per node ----
  const int tb = bid - RB2;
  int n = tid>>4, q = tid&15;
  int node = tb*16 + n;
  float x0=0.f, x1=0.f, x2=0.f;
  if (node < NN){ x0=x[node*3]; x1=x[node*3+1]; x2=x[node*3+2]; }
  float v[8], s=0.f, s2=0.f;
#pragma unroll
  for (int j=0;j<8;j++){
    int c = q*8+j;
    v[j] = eW[c*3]*x0 + eW[c*3+1]*x1 + eW[c*3+2]*x2 + eB[c];
    s += v[j]; s2 += v[j]*v[j];
  }
#pragma unroll
  for (int m=1;m<16;m<<=1){ s += __shfl_xor(s,m,64); s2 += __shfl_xor(s2,m,64); }
  float mean = s*(1.f/128.f);
  float var  = s2*(1.f/128.f) - mean*mean;
  float rsq  = rsqrtf(var + 1e-5f);
  float ho[8];
#pragma unroll
  for (int j=0;j<8;j++){
    int c = q*8+j;
    float y = (v[j]-mean)*rsq*eG[c] + eBB[c];
    ho[j] = y * fsig(y);
  }
  *(float4*)(hg + (size_t)node*HID + q*8)     = make_float4(ho[0],ho[1],ho[2],ho[3]);
  *(float4*)(hg + (size_t)node*HID + q*8 + 4) = make_float4(ho[4],ho[5],ho[6],ho[7]);
  union { f16x2 h2[4]; uint4 u; } pk;
  pk.h2[0] = __builtin_amdgcn_cvt_pkrtz(ho[0],ho[1]);
  pk.h2[1] = __builtin_amdgcn_cvt_pkrtz(ho[2],ho[3]);
  pk.h2[2] = __builtin_amdgcn_cvt_pkrtz(ho[4],ho[5]);
  pk.h2[3] = __builtin_amdgcn_cvt_pkrtz(ho[6],ho[7]);
  *(uint4*)(hfg + (size_t)node*HID + q*8) = pk.u;
}

// ---------------- layer-0 UV GEMM (repacked fp16 weights) ----------------
__global__ __launch_bounds__(256) void k_nodeUV(
    const _Float16* __restrict__ hf,
    const _Float16* __restrict__ wnf, const float* __restrict__ m1b,
    _Float16* __restrict__ UV)
{
  const int tid = threadIdx.x;
  const int wv = tid>>6, lane = tid&63;
  const int col = lane&15, quad = lane>>4;
  const int node = blockIdx.x*16 + col;

  f16x8 bfrag[4];
#pragma unroll
  for (int s=0;s<4;s++)
    bfrag[s] = *(const f16x8*)(hf + (size_t)node*HID + s*32 + quad*8);

  floatx4 acc[8];
#pragma unroll
  for (int i=0;i<8;i++) acc[i] = (floatx4)(0.f);

  const _Float16* wb = wnf + quad*128 + col*8;
#pragma unroll
  for (int s=0;s<4;s++)
#pragma unroll
    for (int mt=0;mt<8;mt++){
      f16x8 a = *(const f16x8*)(wb + (size_t)((wv*8+mt)*4+s)*512);
      acc[mt] = __builtin_amdgcn_mfma_f32_16x16x32_f16(a, bfrag[s], acc[mt], 0,0,0);
    }

#pragma unroll
  for (int mt=0;mt<8;mt++){
    int o0 = wv*128 + mt*16 + quad*4;
    float4 bv = (o0 < 256) ? *(const float4*)(m1b + o0) : make_float4(0.f,0.f,0.f,0.f);
    union { f16x2 h2[2]; uint2 u; } pk;
    pk.h2[0] = __builtin_amdgcn_cvt_pkrtz(acc[mt][0]+bv.x, acc[mt][1]+bv.y);
    pk.h2[1] = __builtin_amdgcn_cvt_pkrtz(acc[mt][2]+bv.z, acc[mt][3]+bv.w);
    *(uint2*)(UV + (size_t)node*512 + o0) = pk.u;
  }
}

// ---------------- fused layer: agg + GEMM2 + gate + LN + next-layer UV ----------------
__global__ __launch_bounds__(512) void k_layer(
    const _Float16* __restrict__ uvin, _Float16* __restrict__ uvout,
    const int2* __restrict__ epk, const int* __restrict__ deg,
    const float* __restrict__ w256l,
    const _Float16* __restrict__ w2fl, const float* __restrict__ b2l,
    const _Float16* __restrict__ gwfl, const float* __restrict__ gbl,
    const float* __restrict__ lngl, const float* __restrict__ lnbl,
    float* __restrict__ hg, _Float16* __restrict__ hfg,
    const _Float16* __restrict__ wnfN, const float* __restrict__ m1bN)
{
  __shared__ _Float16 AggH[16][264];  // [0..127] aggr-f16 (after B); [128..255] new-hf (after C)
  __shared__ float    Agg[16][132];
  __shared__ float    reds[8][16], reds2[8][16];
  const int tid = threadIdx.x;
  const int wv = tid>>6, lane = tid&63;
  const int col = lane&15, quad = lane>>4;
  const int half = lane>>5, sub = lane&31;
  const int n0 = blockIdx.x*16;

  // ---- A: aggregation; wave wv -> nodes {wv*2, wv*2+1}; 8 dims/lane; edges split by half ----
  {
    const int el = sub*8;
    float wcv[8];
    { float4 a = *(const float4*)(w256l + el);
      float4 b = *(const float4*)(w256l + el + 4);
      wcv[0]=a.x; wcv[1]=a.y; wcv[2]=a.z; wcv[3]=a.w;
      wcv[4]=b.x; wcv[5]=b.y; wcv[6]=b.z; wcv[7]=b.w; }
#pragma unroll
    for (int i=0;i<2;i++){
      int nl = wv*2 + i;
      int n = n0 + nl;
      f16x8 uvec = *(const f16x8*)(uvin + (size_t)n*512 + el);
      float U[8], a[8];
#pragma unroll
      for (int j=0;j<8;j++){ U[j] = (float)uvec[j]; a[j] = 0.f; }
      int dg = deg[n]; if (dg > CAP) dg = CAP;
      const int2* pp = epk + (size_t)n*CAP;
      int r = half;
      if (r < dg){
        int2 p0 = pp[r];
        float eav = __int_as_float(p0.y);
        f16x8 vb = *(const f16x8*)(uvin + (size_t)p0.x*512 + 256 + el);
        for (;;){
          int rn = r + 2;
          f16x8 vcur = vb; float eac = eav;
          if (rn < dg){
            int2 p = pp[rn];
            eav = __int_as_float(p.y);
            vb = *(const f16x8*)(uvin + (size_t)p.x*512 + 256 + el);
          }
#pragma unroll
          for (int j=0;j<8;j++){
            float f = U[j] + (float)vcur[j] + eac*wcv[j];
            a[j] += f*fsig(f);
          }
          if (rn >= dg) break;
          r = rn;
        }
      }
#pragma unroll
      for (int j=0;j<8;j++) a[j] += __shfl_xor(a[j], 32, 64);
      if (half == 0){
        union { f16x2 h2[4]; uint4 u; } pk;
        pk.h2[0] = __builtin_amdgcn_cvt_pkrtz(a[0],a[1]);
        pk.h2[1] = __builtin_amdgcn_cvt_pkrtz(a[2],a[3]);
        pk.h2[2] = __builtin_amdgcn_cvt_pkrtz(a[4],a[5]);
        pk.h2[3] = __builtin_amdgcn_cvt_pkrtz(a[6],a[7]);
        *(uint4*)(&AggH[nl][el]) = pk.u;
      }
    }
  }
  __syncthreads();

  // ---- B: GEMM2 over silu-agg; wave wv -> outs [wv*16,+16) ----
  floatx4 acc2 = (floatx4)(0.f);
  {
    const _Float16* wb2 = w2fl + quad*128 + col*8;
#pragma unroll
    for (int s=0;s<8;s++){
      f16x8 b = *(const f16x8*)(&AggH[col][s*32 + quad*8]);
      f16x8 a = *(const f16x8*)(wb2 + (size_t)(wv*8+s)*512);
      acc2 = __builtin_amdgcn_mfma_f32_16x16x32_f16(a, b, acc2, 0,0,0);
    }
  }
  __syncthreads();
  {
    float degf = (float)min(deg[n0+col], CAP);
    int outb = wv*16 + quad*4;
    float4 b2v = *(const float4*)(b2l + outb);
    float v0 = acc2[0] + degf*b2v.x;
    float v1 = acc2[1] + degf*b2v.y;
    float v2 = acc2[2] + degf*b2v.z;
    float v3 = acc2[3] + degf*b2v.w;
    *(float4*)(&Agg[col][outb]) = make_float4(v0,v1,v2,v3);
    union { f16x2 h2[2]; uint2 u; } pk;
    pk.h2[0] = __builtin_amdgcn_cvt_pkrtz(v0,v1);
    pk.h2[1] = __builtin_amdgcn_cvt_pkrtz(v2,v3);
    *(uint2*)(&AggH[col][outb]) = pk.u;
  }
  __syncthreads();

  // ---- C: gate GEMM over [hf(global) ; aggr(LDS)], residual, LN ----
  floatx4 accg = (floatx4)(0.f);
  {
    const int node = n0 + col;
    const _Float16* wbg = gwfl + quad*128 + col*8;
#pragma unroll
    for (int s=0;s<4;s++){
      f16x8 b = *(const f16x8*)(hfg + (size_t)node*HID + s*32 + quad*8);
      f16x8 a = *(const f16x8*)(wbg + (size_t)(wv*8+s)*512);
      accg = __builtin_amdgcn_mfma_f32_16x16x32_f16(a, b, accg, 0,0,0);
    }
#pragma unroll
    for (int s=4;s<8;s++){
      f16x8 b = *(const f16x8*)(&AggH[col][(s-4)*32 + quad*8]);
      f16x8 a = *(const f16x8*)(wbg + (size_t)(wv*8+s)*512);
      accg = __builtin_amdgcn_mfma_f32_16x16x32_f16(a, b, accg, 0,0,0);
    }
  }
  const int outb = wv*16 + quad*4;
  const int node = n0 + col;
  float vvv[4], ss=0.f, ss2=0.f;
  {
    float4 gbv = *(const float4*)(gbl + outb);
    float4 av  = *(const float4*)(&Agg[col][outb]);
    float4 hv  = *(const float4*)(hg + (size_t)node*HID + outb);
    float gg[4] = {gbv.x,gbv.y,gbv.z,gbv.w};
    float aa[4] = {av.x,av.y,av.z,av.w};
    float hh[4] = {hv.x,hv.y,hv.z,hv.w};
#pragma unroll
    for (int r=0;r<4;r++){
      float gate = fsig(accg[r] + gg[r]);
      float v = hh[r] + gate*aa[r] + (1.f-gate)*hh[r];
      vvv[r] = v; ss += v; ss2 += v*v;
    }
  }
  ss  += __shfl_xor(ss, 16, 64);  ss  += __shfl_xor(ss, 32, 64);
  ss2 += __shfl_xor(ss2, 16, 64); ss2 += __shfl_xor(ss2, 32, 64);
  if (quad == 0){ reds[wv][col] = ss; reds2[wv][col] = ss2; }
  __syncthreads();

  {
    float S=0.f, S2=0.f;
#pragma unroll
    for (int w=0;w<8;w++){ S += reds[w][col]; S2 += reds2[w][col]; }
    float mean = S*(1.f/128.f);
    float var  = S2*(1.f/128.f) - mean*mean;
    float rsq  = rsqrtf(var + 1e-5f);
    float4 gv = *(const float4*)(lngl + outb);
    float4 bv = *(const float4*)(lnbl + outb);
    float o0 = (vvv[0]-mean)*rsq*gv.x + bv.x;
    float o1 = (vvv[1]-mean)*rsq*gv.y + bv.y;
    float o2 = (vvv[2]-mean)*rsq*gv.z + bv.z;
    float o3 = (vvv[3]-mean)*rsq*gv.w + bv.w;
    *(float4*)(hg + (size_t)node*HID + outb) = make_float4(o0,o1,o2,o3);
    union { f16x2 h2[2]; uint2 u; } pk;
    pk.h2[0] = __builtin_amdgcn_cvt_pkrtz(o0,o1);
    pk.h2[1] = __builtin_amdgcn_cvt_pkrtz(o2,o3);
    *(uint2*)(hfg + (size_t)node*HID + outb) = pk.u;
    *(uint2*)(&AggH[col][128 + outb]) = pk.u;
  }
  __syncthreads();

  // ---- D: next layer's UV ----
  if (uvout){
    f16x8 bf[4];
#pragma unroll
    for (int s=0;s<4;s++) bf[s] = *(const f16x8*)(&AggH[col][128 + s*32 + quad*8]);
    floatx4 au[4];
#pragma unroll
    for (int i=0;i<4;i++) au[i] = (floatx4)(0.f);
    const _Float16* wbn = wnfN + quad*128 + col*8;
#pragma unroll
    for (int s=0;s<4;s++)
#pragma unroll
      for (int mt=0;mt<4;mt++){
        f16x8 a = *(const f16x8*)(wbn + (size_t)((wv*4+mt)*4+s)*512);
        au[mt] = __builtin_amdgcn_mfma_f32_16x16x32_f16(a, bf[s], au[mt], 0,0,0);
      }
#pragma unroll
    for (int mt=0;mt<4;mt++){
      int o0i = (wv*4+mt)*16 + quad*4;
      float4 buv = (o0i < 256) ? *(const float4*)(m1bN + o0i) : make_float4(0.f,0.f,0.f,0.f);
      union { f16x2 h2[2]; uint2 u; } pu;
      pu.h2[0] = __builtin_amdgcn_cvt_pkrtz(au[mt][0]+buv.x, au[mt][1]+buv.y);
      pu.h2[1] = __builtin_amdgcn_cvt_pkrtz(au[mt][2]+buv.z, au[mt][3]+buv.w);
      *(uint2*)(uvout + (size_t)node*512 + o0i) = pu.u;
    }
  }
}

// ---------------- pooling (binary search) + projector ----------------
__global__ __launch_bounds__(512) void k_fin(
    const float* __restrict__ h, const int* __restrict__ batch,
    const float* __restrict__ p1W, const float* __restrict__ p1b,
    const float* __restrict__ l1g, const float* __restrict__ l1b,
    const float* __restrict__ p2W, const float* __restrict__ p2b,
    const float* __restrict__ l2g, const float* __restrict__ l2b,
    float* __restrict__ out)
{
  __shared__ float xs[4][128];
  __shared__ float xg[128], pbuf[128], redf[4];
  const int g = blockIdx.x, tid = threadIdx.x;
  const int c = tid & 127, part = tid >> 7;
  int lo, hi;
  { int L=0, r=NN;
    while (L<r){ int m=(L+r)>>1; if (batch[m]<g) L=m+1; else r=m; }
    lo = L; r = NN;
    while (L<r){ int m=(L+r)>>1; if (batch[m]<g+1) L=m+1; else r=m; }
    hi = L; }
  float s = 0.f;
  for (int n = lo+part; n < hi; n += 4) s += h[(size_t)n*HID + c];
  xs[part][c] = s;
  __syncthreads();
  if (tid < 128){
    float cnt = (float)(hi-lo);
    float S = xs[0][c]+xs[1][c]+xs[2][c]+xs[3][c];
    float xgv = S * (1.f/fmaxf(cnt,1.f) + 1.f/(cnt + 1e-6f));
    out[NG*64 + g*HID + c] = xgv;
    xg[c] = xgv;
  }
  __syncthreads();
  {
    float vp = 0.f;
    for (int k = part*32; k < (part+1)*32; k++) vp += xg[k]*p1W[c*HID + k];
    xs[part][c] = vp;
  }
  __syncthreads();
  float v = 0.f;
  if (tid < 128){
    v = p1b[c] + xs[0][c]+xs[1][c]+xs[2][c]+xs[3][c];
    float sv=v, sv2=v*v;
#pragma unroll
    for (int m=1;m<64;m<<=1){ sv+=__shfl_xor(sv,m,64); sv2+=__shfl_xor(sv2,m,64); }
    if ((c&63)==0){ redf[(c>>6)*2]=sv; redf[(c>>6)*2+1]=sv2; }
  }
  __syncthreads();
  if (tid < 128){
    float S=redf[0]+redf[2], S2=redf[1]+redf[3];
    float mean=S*(1.f/128.f), var=S2*(1.f/128.f)-mean*mean;
    float y=(v-mean)*rsqrtf(var+1e-5f)*l1g[c]+l1b[c];
    pbuf[c] = y*fsig(y);
  }
  __syncthreads();
  if (tid < 64){
    float z = p2b[tid];
    for (int k=0;k<HID;k++) z += pbuf[k]*p2W[tid*HID + k];
    float t=z, t2=z*z;
#pragma unroll
    for (int m=1;m<64;m<<=1){ t+=__shfl_xor(t,m,64); t2+=__shfl_xor(t2,m,64); }
    float mn=t*(1.f/64.f), vr=t2*(1.f/64.f)-mn*mn;
    out[g*64 + tid] = (z-mn)*rsqrtf(vr+1e-5f)*l2g[tid]+l2b[tid];
  }
}

extern "C" void kernel_launch(void* const* d_in, const int* in_sizes, int n_in,
                              void* d_out, int out_size, void* d_ws, size_t ws_size,
                              hipStream_t stream){
  const float* x     = (const float*)d_in[0];
  const float* ea    = (const float*)d_in[1];
  const int*   ei    = (const int*)  d_in[2];
  const int*   batch = (const int*)  d_in[3];
  const float* embW  = (const float*)d_in[4];
  const float* embB  = (const float*)d_in[5];
  const float* embG  = (const float*)d_in[6];
  const float* embBe = (const float*)d_in[7];
  const float* m1W   = (const float*)d_in[8];
  const float* m1b   = (const float*)d_in[9];
  const float* m2W   = (const float*)d_in[10];
  const float* m2b   = (const float*)d_in[11];
  const float* gW    = (const float*)d_in[12];
  const float* gb    = (const float*)d_in[13];
  const float* lng   = (const float*)d_in[14];
  const float* lnb   = (const float*)d_in[15];
  const float* p1W   = (const float*)d_in[16];
  const float* p1b   = (const float*)d_in[17];
  const float* l1g   = (const float*)d_in[18];
  const float* l1b   = (const float*)d_in[19];
  const float* p2W   = (const float*)d_in[20];
  const float* p2b   = (const float*)d_in[21];
  const float* l2g   = (const float*)d_in[22];
  const float* l2b   = (const float*)d_in[23];

  char* p = (char*)d_ws;
  auto alloc = [&](size_t bytes){ char* r = p; p += (bytes + 255) & ~(size_t)255; return r; };
  float*     hg   = (float*)     alloc((size_t)NNP*HID*4);
  _Float16*  hfg  = (_Float16*)  alloc((size_t)NNP*HID*2);
  _Float16*  UVa  = (_Float16*)  alloc((size_t)NNP*512*2);
  _Float16*  UVb  = (_Float16*)  alloc((size_t)NNP*512*2);
  _Float16*  wnf  = (_Float16*)  alloc((size_t)NL*65536*2);
  _Float16*  w2f  = (_Float16*)  alloc((size_t)NL*32768*2);
  _Float16*  gwf  = (_Float16*)  alloc((size_t)NL*32768*2);
  float*     w256 = (float*)     alloc((size_t)NL*256*4);
  int*       deg  = (int*)       alloc((size_t)NNP*4);
  int2*      epk  = (int2*)      alloc((size_t)NNP*CAP*8);

  hipMemsetAsync(deg, 0, (size_t)NNP*4, stream);

  k_setup<<<RB3, 256, 0, stream>>>(
      m1W, m2W, gW, ei, ea, x, embW, embB, embG, embBe,
      wnf, w2f, gwf, w256, deg, epk, hg, hfg);

  k_nodeUV<<<NNP/16, 256, 0, stream>>>(hfg, wnf, m1b, UVa);

  for (int l=0; l<NL; l++){
    bool last = (l == NL-1);
    _Float16* uvin  = (l&1) ? UVb : UVa;
    _Float16* uvout = last ? nullptr : ((l&1) ? UVa : UVb);
    k_layer<<<NNP/16, 512, 0, stream>>>(
        uvin, uvout, epk, deg,
        w256 + l*256, w2f + (size_t)l*32768, m2b + l*128,
        gwf + (size_t)l*32768, gb + l*128,
        lng + l*128, lnb + l*128,
        hg, hfg,
        last ? (const _Float16*)nullptr : (wnf + (size_t)(l+1)*65536),
        m1b + (last ? 0 : (l+1)*256));
  }
  k_fin<<<NG, 512, 0, stream>>>(hg, batch, p1W, p1b, l1g, l1b,
                                p2W, p2b, l2g, l2b, (float*)d_out);
}

// Round 14
// 246.359 us; speedup vs baseline: 1.1262x; 1.0214x over previous
//
#include <hip/hip_runtime.h>

#define NN 10000
#define NNP 10048
#define NE 160000
#define NG 64
#define HID 128
#define NL 3
#define CAP 64      // per-node edge slots (Poisson(16); P(deg>64) ~ 1e-20)

typedef float floatx4 __attribute__((ext_vector_type(4)));
typedef _Float16 f16x8 __attribute__((ext_vector_type(8)));
typedef __fp16 f16x2 __attribute__((ext_vector_type(2)));

__device__ __forceinline__ float fsig(float x){
  return __builtin_amdgcn_rcpf(1.f + __expf(-x));
}

// repack domain: wnf all 3 layers
#define RZ_A (NL*65536)
#define RZ_B (RZ_A + NL*32768)
#define RZ_C (RZ_B + NL*32768)
#define RZ_D (RZ_C + NL*256)     // = 393984
#define RB1  ((RZ_D + 255)/256)  // 1539
#define RB2  (RB1 + 157)         // edge-placement blocks (157*1024 >= 160000)
#define RB3  (RB2 + 628)         // embed blocks (1 tile each)

// ---------------- setup: repack || edge binning || embed ----------------
__global__ __launch_bounds__(256) void k_setup(
    const float* __restrict__ m1, const float* __restrict__ m2,
    const float* __restrict__ mg,
    const int* __restrict__ ei, const float* __restrict__ ea,
    const float* __restrict__ x,
    const float* __restrict__ eW, const float* __restrict__ eB,
    const float* __restrict__ eG, const float* __restrict__ eBB,
    _Float16* __restrict__ wnf, _Float16* __restrict__ w2f,
    _Float16* __restrict__ gwf, float* __restrict__ w256,
    int* __restrict__ deg, int2* __restrict__ epk,
    _Float16* __restrict__ hfg)
{
  const int bid = blockIdx.x, tid = threadIdx.x;
  if (bid < RB1){
    int i = bid*256 + tid;
    if (i < RZ_A){
      int l = i>>16, j = i & 65535;
      int t=j&7, col=(j>>3)&15, quad=(j>>7)&3, s=(j>>9)&3, mb=(j>>11)&31;
      int o = mb*16+col, k = s*32+quad*8+t;
      float v = (o<256) ? m1[l*65792 + o*257 + k] : m1[l*65792 + (o-256)*257 + 128 + k];
      wnf[i] = (_Float16)v;
    } else if (i < RZ_B){
      int j=i-RZ_A; int l=j>>15; j&=32767;
      int t=j&7, col=(j>>3)&15, quad=(j>>7)&3, s=(j>>9)&7, mb=(j>>12)&7;
      w2f[(l<<15)+j] = (_Float16)m2[l*32768 + (mb*16+col)*256 + s*32+quad*8+t];
    } else if (i < RZ_C){
      int j=i-RZ_B; int l=j>>15; j&=32767;
      int t=j&7, col=(j>>3)&15, quad=(j>>7)&3, s=(j>>9)&7, mb=(j>>12)&7;
      gwf[(l<<15)+j] = (_Float16)mg[l*32768 + (mb*16+col)*256 + s*32+quad*8+t];
    } else if (i < RZ_D){
      int j=i-RZ_C; int l=j>>8, o=j&255;
      w256[j] = m1[l*65792 + o*257 + 256];
    }
    return;
  }
  if (bid < RB2){
    int e4 = ((bid-RB1)*256 + tid)*4;
    if (e4 < NE){
      int4   s4 = *(const int4*)(ei + e4);
      int4   d4 = *(const int4*)(ei + NE + e4);
      float4 a4 = *(const float4*)(ea + e4);
      int ds[4] = {d4.x, d4.y, d4.z, d4.w};
      int sr[4] = {s4.x, s4.y, s4.z, s4.w};
      float av[4] = {a4.x, a4.y, a4.z, a4.w};
#pragma unroll
      for (int j=0;j<4;j++){
        int slot = atomicAdd(&deg[ds[j]], 1) & (CAP-1);
        int2 pk; pk.x = sr[j]; pk.y = __float_as_int(av[j]);
        epk[(size_t)ds[j]*CAP + slot] = pk;
      }
    }
    return;
  }
  // ---- embed: 16 nodes, 16 threads per node ----
  const int tb = bid - RB2;
  int n = tid>>4, q = tid&15;
  int node = tb*16 + n;
  float x0=0.f, x1=0.f, x2=0.f;
  if (node < NN){ x0=x[node*3]; x1=x[node*3+1]; x2=x[node*3+2]; }
  float v[8], s=0.f, s2=0.f;
#pragma unroll
  for (int j=0;j<8;j++){
    int c = q*8+j;
    v[j] = eW[c*3]*x0 + eW[c*3+1]*x1 + eW[c*3+2]*x2 + eB[c];
    s += v[j]; s2 += v[j]*v[j];
  }
#pragma unroll
  for (int m=1;m<16;m<<=1){ s += __shfl_xor(s,m,64); s2 += __shfl_xor(s2,m,64); }
  float mean = s*(1.f/128.f);
  float var  = s2*(1.f/128.f) - mean*mean;
  float rsq  = rsqrtf(var + 1e-5f);
  float ho[8];
#pragma unroll
  for (int j=0;j<8;j++){
    int c = q*8+j;
    float y = (v[j]-mean)*rsq*eG[c] + eBB[c];
    ho[j] = y * fsig(y);
  }
  union { f16x2 h2[4]; uint4 u; } pk;
  pk.h2[0] = __builtin_amdgcn_cvt_pkrtz(ho[0],ho[1]);
  pk.h2[1] = __builtin_amdgcn_cvt_pkrtz(ho[2],ho[3]);
  pk.h2[2] = __builtin_amdgcn_cvt_pkrtz(ho[4],ho[5]);
  pk.h2[3] = __builtin_amdgcn_cvt_pkrtz(ho[6],ho[7]);
  *(uint4*)(hfg + (size_t)node*HID + q*8) = pk.u;
}

// ---------------- layer-0 UV GEMM (repacked fp16 weights) ----------------
__global__ __launch_bounds__(256) void k_nodeUV(
    const _Float16* __restrict__ hf,
    const _Float16* __restrict__ wnf, const float* __restrict__ m1b,
    _Float16* __restrict__ UV)
{
  const int tid = threadIdx.x;
  const int wv = tid>>6, lane = tid&63;
  const int col = lane&15, quad = lane>>4;
  const int node = blockIdx.x*16 + col;

  f16x8 bfrag[4];
#pragma unroll
  for (int s=0;s<4;s++)
    bfrag[s] = *(const f16x8*)(hf + (size_t)node*HID + s*32 + quad*8);

  floatx4 acc[8];
#pragma unroll
  for (int i=0;i<8;i++) acc[i] = (floatx4)(0.f);

  const _Float16* wb = wnf + quad*128 + col*8;
#pragma unroll
  for (int s=0;s<4;s++)
#pragma unroll
    for (int mt=0;mt<8;mt++){
      f16x8 a = *(const f16x8*)(wb + (size_t)((wv*8+mt)*4+s)*512);
      acc[mt] = __builtin_amdgcn_mfma_f32_16x16x32_f16(a, bfrag[s], acc[mt], 0,0,0);
    }

#pragma unroll
  for (int mt=0;mt<8;mt++){
    int o0 = wv*128 + mt*16 + quad*4;
    float4 bv = (o0 < 256) ? *(const float4*)(m1b + o0) : make_float4(0.f,0.f,0.f,0.f);
    union { f16x2 h2[2]; uint2 u; } pk;
    pk.h2[0] = __builtin_amdgcn_cvt_pkrtz(acc[mt][0]+bv.x, acc[mt][1]+bv.y);
    pk.h2[1] = __builtin_amdgcn_cvt_pkrtz(acc[mt][2]+bv.z, acc[mt][3]+bv.w);
    *(uint2*)(UV + (size_t)node*512 + o0) = pk.u;
  }
}

// ---------------- fused layer: agg + GEMM2 + gate + LN + next-layer UV ----------------
__global__ __launch_bounds__(512) void k_layer(
    const _Float16* __restrict__ uvin, _Float16* __restrict__ uvout,
    const int2* __restrict__ epk, const int* __restrict__ deg,
    const float* __restrict__ w256l,
    const _Float16* __restrict__ w2fl, const float* __restrict__ b2l,
    const _Float16* __restrict__ gwfl, const float* __restrict__ gbl,
    const float* __restrict__ lngl, const float* __restrict__ lnbl,
    _Float16* __restrict__ hfg,
    const _Float16* __restrict__ wnfN, const float* __restrict__ m1bN)
{
  __shared__ _Float16 AggH[16][264];  // [0..127] aggr-f16 (after B); [128..255] new-hf (after C)
  __shared__ float    Agg[16][132];
  __shared__ float    reds[8][16], reds2[8][16];
  const int tid = threadIdx.x;
  const int wv = tid>>6, lane = tid&63;
  const int col = lane&15, quad = lane>>4;
  const int half = lane>>5, sub = lane&31;
  const int n0 = blockIdx.x*16;

  // ---- A: aggregation; wave wv -> nodes {wv*2, wv*2+1}; 8 dims/lane; edges split by half ----
  {
    const int el = sub*8;
    float wcv[8];
    { float4 a = *(const float4*)(w256l + el);
      float4 b = *(const float4*)(w256l + el + 4);
      wcv[0]=a.x; wcv[1]=a.y; wcv[2]=a.z; wcv[3]=a.w;
      wcv[4]=b.x; wcv[5]=b.y; wcv[6]=b.z; wcv[7]=b.w; }
#pragma unroll
    for (int i=0;i<2;i++){
      int nl = wv*2 + i;
      int n = n0 + nl;
      f16x8 uvec = *(const f16x8*)(uvin + (size_t)n*512 + el);
      float U[8], a[8];
#pragma unroll
      for (int j=0;j<8;j++){ U[j] = (float)uvec[j]; a[j] = 0.f; }
      int dg = deg[n]; if (dg > CAP) dg = CAP;
      const int2* pp = epk + (size_t)n*CAP;
      int r = half;
      if (r < dg){
        int2 p0 = pp[r];
        float eav = __int_as_float(p0.y);
        f16x8 vb = *(const f16x8*)(uvin + (size_t)p0.x*512 + 256 + el);
        for (;;){
          int rn = r + 2;
          f16x8 vcur = vb; float eac = eav;
          if (rn < dg){
            int2 p = pp[rn];
            eav = __int_as_float(p.y);
            vb = *(const f16x8*)(uvin + (size_t)p.x*512 + 256 + el);
          }
#pragma unroll
          for (int j=0;j<8;j++){
            float f = U[j] + (float)vcur[j] + eac*wcv[j];
            a[j] += f*fsig(f);
          }
          if (rn >= dg) break;
          r = rn;
        }
      }
#pragma unroll
      for (int j=0;j<8;j++) a[j] += __shfl_xor(a[j], 32, 64);
      if (half == 0){
        union { f16x2 h2[4]; uint4 u; } pk;
        pk.h2[0] = __builtin_amdgcn_cvt_pkrtz(a[0],a[1]);
        pk.h2[1] = __builtin_amdgcn_cvt_pkrtz(a[2],a[3]);
        pk.h2[2] = __builtin_amdgcn_cvt_pkrtz(a[4],a[5]);
        pk.h2[3] = __builtin_amdgcn_cvt_pkrtz(a[6],a[7]);
        *(uint4*)(&AggH[nl][el]) = pk.u;
      }
    }
  }
  __syncthreads();

  // ---- B: GEMM2 over silu-agg; wave wv -> outs [wv*16,+16) ----
  floatx4 acc2 = (floatx4)(0.f);
  {
    const _Float16* wb2 = w2fl + quad*128 + col*8;
#pragma unroll
    for (int s=0;s<8;s++){
      f16x8 b = *(const f16x8*)(&AggH[col][s*32 + quad*8]);
      f16x8 a = *(const f16x8*)(wb2 + (size_t)(wv*8+s)*512);
      acc2 = __builtin_amdgcn_mfma_f32_16x16x32_f16(a, b, acc2, 0,0,0);
    }
  }
  __syncthreads();
  {
    float degf = (float)min(deg[n0+col], CAP);
    int outb = wv*16 + quad*4;
    float4 b2v = *(const float4*)(b2l + outb);
    float v0 = acc2[0] + degf*b2v.x;
    float v1 = acc2[1] + degf*b2v.y;
    float v2 = acc2[2] + degf*b2v.z;
    float v3 = acc2[3] + degf*b2v.w;
    *(float4*)(&Agg[col][outb]) = make_float4(v0,v1,v2,v3);
    union { f16x2 h2[2]; uint2 u; } pk;
    pk.h2[0] = __builtin_amdgcn_cvt_pkrtz(v0,v1);
    pk.h2[1] = __builtin_amdgcn_cvt_pkrtz(v2,v3);
    *(uint2*)(&AggH[col][outb]) = pk.u;
  }
  __syncthreads();

  // ---- C: gate GEMM over [hf(global) ; aggr(LDS)], residual, LN ----
  floatx4 accg = (floatx4)(0.f);
  {
    const int node = n0 + col;
    const _Float16* wbg = gwfl + quad*128 + col*8;
#pragma unroll
    for (int s=0;s<4;s++){
      f16x8 b = *(const f16x8*)(hfg + (size_t)node*HID + s*32 + quad*8);
      f16x8 a = *(const f16x8*)(wbg + (size_t)(wv*8+s)*512);
      accg = __builtin_amdgcn_mfma_f32_16x16x32_f16(a, b, accg, 0,0,0);
    }
#pragma unroll
    for (int s=4;s<8;s++){
      f16x8 b = *(const f16x8*)(&AggH[col][(s-4)*32 + quad*8]);
      f16x8 a = *(const f16x8*)(wbg + (size_t)(wv*8+s)*512);
      accg = __builtin_amdgcn_mfma_f32_16x16x32_f16(a, b, accg, 0,0,0);
    }
  }
  const int outb = wv*16 + quad*4;
  const int node = n0 + col;
  float vvv[4], ss=0.f, ss2=0.f;
  {
    float4 gbv = *(const float4*)(gbl + outb);
    float4 av  = *(const float4*)(&Agg[col][outb]);
    union { uint2 u; _Float16 hx[4]; } hv;
    hv.u = *(const uint2*)(hfg + (size_t)node*HID + outb);
    float gg[4] = {gbv.x,gbv.y,gbv.z,gbv.w};
    float aa[4] = {av.x,av.y,av.z,av.w};
#pragma unroll
    for (int r=0;r<4;r++){
      float hh = (float)hv.hx[r];
      float gate = fsig(accg[r] + gg[r]);
      float v = hh + gate*aa[r] + (1.f-gate)*hh;
      vvv[r] = v; ss += v; ss2 += v*v;
    }
  }
  ss  += __shfl_xor(ss, 16, 64);  ss  += __shfl_xor(ss, 32, 64);
  ss2 += __shfl_xor(ss2, 16, 64); ss2 += __shfl_xor(ss2, 32, 64);
  if (quad == 0){ reds[wv][col] = ss; reds2[wv][col] = ss2; }
  __syncthreads();

  {
    float S=0.f, S2=0.f;
#pragma unroll
    for (int w=0;w<8;w++){ S += reds[w][col]; S2 += reds2[w][col]; }
    float mean = S*(1.f/128.f);
    float var  = S2*(1.f/128.f) - mean*mean;
    float rsq  = rsqrtf(var + 1e-5f);
    float4 gv = *(const float4*)(lngl + outb);
    float4 bv = *(const float4*)(lnbl + outb);
    float o0 = (vvv[0]-mean)*rsq*gv.x + bv.x;
    float o1 = (vvv[1]-mean)*rsq*gv.y + bv.y;
    float o2 = (vvv[2]-mean)*rsq*gv.z + bv.z;
    float o3 = (vvv[3]-mean)*rsq*gv.w + bv.w;
    union { f16x2 h2[2]; uint2 u; } pk;
    pk.h2[0] = __builtin_amdgcn_cvt_pkrtz(o0,o1);
    pk.h2[1] = __builtin_amdgcn_cvt_pkrtz(o2,o3);
    *(uint2*)(hfg + (size_t)node*HID + outb) = pk.u;
    *(uint2*)(&AggH[col][128 + outb]) = pk.u;
  }
  __syncthreads();

  // ---- D: next layer's UV ----
  if (uvout){
    f16x8 bf[4];
#pragma unroll
    for (int s=0;s<4;s++) bf[s] = *(const f16x8*)(&AggH[col][128 + s*32 + quad*8]);
    floatx4 au[4];
#pragma unroll
    for (int i=0;i<4;i++) au[i] = (floatx4)(0.f);
    const _Float16* wbn = wnfN + quad*128 + col*8;
#pragma unroll
    for (int s=0;s<4;s++)
#pragma unroll
      for (int mt=0;mt<4;mt++){
        f16x8 a = *(const f16x8*)(wbn + (size_t)((wv*4+mt)*4+s)*512);
        au[mt] = __builtin_amdgcn_mfma_f32_16x16x32_f16(a, bf[s], au[mt], 0,0,0);
      }
#pragma unroll
    for (int mt=0;mt<4;mt++){
      int o0i = (wv*4+mt)*16 + quad*4;
      float4 buv = (o0i < 256) ? *(const float4*)(m1bN + o0i) : make_float4(0.f,0.f,0.f,0.f);
      union { f16x2 h2[2]; uint2 u; } pu;
      pu.h2[0] = __builtin_amdgcn_cvt_pkrtz(au[mt][0]+buv.x, au[mt][1]+buv.y);
      pu.h2[1] = __builtin_amdgcn_cvt_pkrtz(au[mt][2]+buv.z, au[mt][3]+buv.w);
      *(uint2*)(uvout + (size_t)node*512 + o0i) = pu.u;
    }
  }
}

// ---------------- pooling (binary search) + projector ----------------
__global__ __launch_bounds__(512) void k_fin(
    const _Float16* __restrict__ hf, const int* __restrict__ batch,
    const float* __restrict__ p1W, const float* __restrict__ p1b,
    const float* __restrict__ l1g, const float* __restrict__ l1b,
    const float* __restrict__ p2W, const float* __restrict__ p2b,
    const float* __restrict__ l2g, const float* __restrict__ l2b,
    float* __restrict__ out)
{
  __shared__ float xs[4][128];
  __shared__ float xg[128], pbuf[128], redf[4];
  const int g = blockIdx.x, tid = threadIdx.x;
  const int c = tid & 127, part = tid >> 7;
  int lo, hi;
  { int L=0, r=NN;
    while (L<r){ int m=(L+r)>>1; if (batch[m]<g) L=m+1; else r=m; }
    lo = L; r = NN;
    while (L<r){ int m=(L+r)>>1; if (batch[m]<g+1) L=m+1; else r=m; }
    hi = L; }
  float s = 0.f;
  for (int n = lo+part; n < hi; n += 4) s += (float)hf[(size_t)n*HID + c];
  xs[part][c] = s;
  __syncthreads();
  if (tid < 128){
    float cnt = (float)(hi-lo);
    float S = xs[0][c]+xs[1][c]+xs[2][c]+xs[3][c];
    float xgv = S * (1.f/fmaxf(cnt,1.f) + 1.f/(cnt + 1e-6f));
    out[NG*64 + g*HID + c] = xgv;
    xg[c] = xgv;
  }
  __syncthreads();
  {
    float vp = 0.f;
    for (int k = part*32; k < (part+1)*32; k++) vp += xg[k]*p1W[c*HID + k];
    xs[part][c] = vp;
  }
  __syncthreads();
  float v = 0.f;
  if (tid < 128){
    v = p1b[c] + xs[0][c]+xs[1][c]+xs[2][c]+xs[3][c];
    float sv=v, sv2=v*v;
#pragma unroll
    for (int m=1;m<64;m<<=1){ sv+=__shfl_xor(sv,m,64); sv2+=__shfl_xor(sv2,m,64); }
    if ((c&63)==0){ redf[(c>>6)*2]=sv; redf[(c>>6)*2+1]=sv2; }
  }
  __syncthreads();
  if (tid < 128){
    float S=redf[0]+redf[2], S2=redf[1]+redf[3];
    float mean=S*(1.f/128.f), var=S2*(1.f/128.f)-mean*mean;
    float y=(v-mean)*rsqrtf(var+1e-5f)*l1g[c]+l1b[c];
    pbuf[c] = y*fsig(y);
  }
  __syncthreads();
  if (tid < 64){
    float z = p2b[tid];
    for (int k=0;k<HID;k++) z += pbuf[k]*p2W[tid*HID + k];
    float t=z, t2=z*z;
#pragma unroll
    for (int m=1;m<64;m<<=1){ t+=__shfl_xor(t,m,64); t2+=__shfl_xor(t2,m,64); }
    float mn=t*(1.f/64.f), vr=t2*(1.f/64.f)-mn*mn;
    out[g*64 + tid] = (z-mn)*rsqrtf(vr+1e-5f)*l2g[tid]+l2b[tid];
  }
}

extern "C" void kernel_launch(void* const* d_in, const int* in_sizes, int n_in,
                              void* d_out, int out_size, void* d_ws, size_t ws_size,
                              hipStream_t stream){
  const float* x     = (const float*)d_in[0];
  const float* ea    = (const float*)d_in[1];
  const int*   ei    = (const int*)  d_in[2];
  const int*   batch = (const int*)  d_in[3];
  const float* embW  = (const float*)d_in[4];
  const float* embB  = (const float*)d_in[5];
  const float* embG  = (const float*)d_in[6];
  const float* embBe = (const float*)d_in[7];
  const float* m1W   = (const float*)d_in[8];
  const float* m1b   = (const float*)d_in[9];
  const float* m2W   = (const float*)d_in[10];
  const float* m2b   = (const float*)d_in[11];
  const float* gW    = (const float*)d_in[12];
  const float* gb    = (const float*)d_in[13];
  const float* lng   = (const float*)d_in[14];
  const float* lnb   = (const float*)d_in[15];
  const float* p1W   = (const float*)d_in[16];
  const float* p1b   = (const float*)d_in[17];
  const float* l1g   = (const float*)d_in[18];
  const float* l1b   = (const float*)d_in[19];
  const float* p2W   = (const float*)d_in[20];
  const float* p2b   = (const float*)d_in[21];
  const float* l2g   = (const float*)d_in[22];
  const float* l2b   = (const float*)d_in[23];

  char* p = (char*)d_ws;
  auto alloc = [&](size_t bytes){ char* r = p; p += (bytes + 255) & ~(size_t)255; return r; };
  _Float16*  hfg  = (_Float16*)  alloc((size_t)NNP*HID*2);
  _Float16*  UVa  = (_Float16*)  alloc((size_t)NNP*512*2);
  _Float16*  UVb  = (_Float16*)  alloc((size_t)NNP*512*2);
  _Float16*  wnf  = (_Float16*)  alloc((size_t)NL*65536*2);
  _Float16*  w2f  = (_Float16*)  alloc((size_t)NL*32768*2);
  _Float16*  gwf  = (_Float16*)  alloc((size_t)NL*32768*2);
  float*     w256 = (float*)     alloc((size_t)NL*256*4);
  int*       deg  = (int*)       alloc((size_t)NNP*4);
  int2*      epk  = (int2*)      alloc((size_t)NNP*CAP*8);

  hipMemsetAsync(deg, 0, (size_t)NNP*4, stream);

  k_setup<<<RB3, 256, 0, stream>>>(
      m1W, m2W, gW, ei, ea, x, embW, embB, embG, embBe,
      wnf, w2f, gwf, w256, deg, epk, hfg);

  k_nodeUV<<<NNP/16, 256, 0, stream>>>(hfg, wnf, m1b, UVa);

  for (int l=0; l<NL; l++){
    bool last = (l == NL-1);
    _Float16* uvin  = (l&1) ? UVb : UVa;
    _Float16* uvout = last ? nullptr : ((l&1) ? UVa : UVb);
    k_layer<<<NNP/16, 512, 0, stream>>>(
        uvin, uvout, epk, deg,
        w256 + l*256, w2f + (size_t)l*32768, m2b + l*128,
        gwf + (size_t)l*32768, gb + l*128,
        lng + l*128, lnb + l*128,
        hfg,
        last ? (const _Float16*)nullptr : (wnf + (size_t)(l+1)*65536),
        m1b + (last ? 0 : (l+1)*256));
  }
  k_fin<<<NG, 512, 0, stream>>>(hfg, batch, p1W, p1b, l1g, l1b,
                                p2W, p2b, l2g, l2b, (float*)d_out);
}